// Round 1
// 62.217 us; speedup vs baseline: 1.0823x; 1.0823x over previous
//
#include <hip/hip_runtime.h>
#include <math.h>

// IntraVolume_Attention, algebraically collapsed:
//   s_f = sum_g x_g e^{c x_f x_g} / sum_g e^{c x_f x_g},  c = dot(wq,wk)/sqrt(128)
//   out[row,d] = wv[d] * mean_f s_f
//
// R7: logits are rank-1 -> s_f is the empirical MGF ratio at t_f = c*x_f.
// With u = x/xmax, tau_f = c*x_f*xmax:
//   den_f = sum_n tau^n/n! * M_n,   num_f = xmax * sum_n tau^n/n! * M_{n+1}
// where M_n = sum_g u_g^n (64 moments shared by all 512 f). Replaces the
// O(F^2)=262k exp/row trans-bound loop (~22 cyc / 2 elems, ~4.7us issue)
// with O(F*N) VALU work (~2us kernel). Guarded: falls back to the exact
// exp path (R6 kernel, verbatim) when |tau|max > 26 (truncation) or the
// cancellation amplification exponent G = taumax*(1 - minside/absmax) > 3.

#if __has_builtin(__builtin_amdgcn_exp2f)
#define EXP2(x) __builtin_amdgcn_exp2f(x)   // raw v_exp_f32
#else
#define EXP2(x) exp2f(x)
#endif

typedef float v2f __attribute__((ext_vector_type(2)));

#define F_DIM 512
#define NTERM 64          // series terms n = 0..63; moments M_0..M_65
#define ROWW 34           // pow row: slot0 = u, slot s = w^s (w = u^2), s=1..33

__global__ __launch_bounds__(1024) void intravol_attn(
    const float* __restrict__ x,    // [256, 512]
    const float* __restrict__ wq,   // [128]
    const float* __restrict__ wk,   // [128]
    const float* __restrict__ wv,   // [128]
    float* __restrict__ out)        // [256, 128]
{
    // pool is a union: series path uses pow[512][34] (69.6 KB) then v2f[1024]
    // partials; fallback path uses pden[4][512]+pnum[4][512] (16 KB).
    __shared__ __align__(16) float pool[F_DIM * ROWW];
    __shared__ __align__(16) float xs[F_DIM];
    __shared__ v2f   pm2[33][17];          // per-chunk partial moment pairs
    __shared__ float mom[NTERM + 2];       // M_0..M_65
    __shared__ float wmax[8], wmin[8], wsum[8];
    __shared__ float s_c, s_xmax, s_xmin, s_scale, s_inv;
    __shared__ int   s_fast;

    const int tid  = threadIdx.x;
    const int lane = tid & 63;
    const int wave = tid >> 6;
    const int row  = blockIdx.x;

    // ---- Phase 0: stage row, reduce max/min (waves 0..7), c (wave 8) ----
    float xv = 0.0f;
    if (tid < F_DIM) { xv = x[row * F_DIM + tid]; xs[tid] = xv; }
    if (wave < 8) {
        float mx = xv, mn = xv;
        for (int o = 32; o > 0; o >>= 1) {
            mx = fmaxf(mx, __shfl_down(mx, o));
            mn = fminf(mn, __shfl_down(mn, o));
        }
        if (lane == 0) { wmax[wave] = mx; wmin[wave] = mn; }
    } else if (wave == 8) {
        float d = wq[lane] * wk[lane] + wq[lane + 64] * wk[lane + 64];
        for (int o = 32; o > 0; o >>= 1) d += __shfl_down(d, o);
        if (lane == 0) s_c = d * 0.08838834764831845f;
    }
    __syncthreads();
    if (tid == 0) {
        float M = wmax[0], m_ = wmin[0];
        #pragma unroll
        for (int i = 1; i < 8; ++i) { M = fmaxf(M, wmax[i]); m_ = fminf(m_, wmin[i]); }
        s_xmax = M; s_xmin = m_;
        const float ap = fmaxf(M, 0.0f), an = fmaxf(-m_, 0.0f);
        const float xa = fmaxf(fmaxf(ap, an), 1e-30f);
        const float tm = fabsf(s_c) * xa * xa;             // max |tau|
        const float ms = fminf(ap, an) / xa;               // minority-side ratio
        s_scale = xa;
        s_inv   = 1.0f / xa;
        // G = tm*(1-ms): cancellation amplification exponent of the series.
        s_fast = (tm <= 26.0f) && (tm * (1.0f - ms) <= 3.0f) ? 1 : 0;
    }
    __syncthreads();

    float sf = 0.0f;

    if (s_fast) {
        // ---- Phase A: power table. Thread g writes {u, w, w^2, w^3, ...} ----
        if (tid < F_DIM) {
            const float u  = xv * s_inv;
            const float w  = u * u;
            const float w2 = w * w;
            v2f* rowp = (v2f*)&pool[tid * ROWW];
            v2f first; first.x = u; first.y = w;
            rowp[0] = first;                        // slots {0,1} = {u, w}
            v2f pr;  pr.x = w2; pr.y = w2 * w;      // {w^2, w^3}
            v2f ww;  ww.x = w2; ww.y = w2;
            #pragma unroll
            for (int m = 1; m <= 16; ++m) {         // slots {2m, 2m+1}
                rowp[m] = pr;
                pr *= ww;                           // v_pk_mul_f32
            }
        }
        __syncthreads();

        // ---- Phase B: partial moments. Thread (k=lane<=32, chunk=wave):
        //   sw = sum_g w^k  = M_{2k}   (k=0: sum u = M_1)
        //   su = sum_g u*w^k = M_{2k+1} (k=0: sum u^2 = M_2)
        if (lane <= 32) {
            const float* rowbase = &pool[(wave << 5) * ROWW];
            float sw = 0.0f, su = 0.0f;
            #pragma unroll
            for (int j = 0; j < 32; ++j) {
                const float rp = rowbase[j * ROWW + lane];
                const float ru = rowbase[j * ROWW];          // broadcast u_g
                sw += rp;
                su  = fmaf(rp, ru, su);
            }
            v2f t; t.x = sw; t.y = su;
            pm2[lane][wave] = t;
        }
        __syncthreads();
        if (tid < 33) {
            v2f s; s.x = 0.0f; s.y = 0.0f;
            #pragma unroll
            for (int c = 0; c < 16; ++c) s += pm2[tid][c];
            if (tid == 0) {
                mom[0] = (float)F_DIM;              // M_0 = 512
                mom[1] = s.x;  mom[2] = s.y;        // M_1, M_2
            } else {
                mom[2 * tid]     = s.x;             // M_{2k}  (k>=1; M_2 dup ok)
                mom[2 * tid + 1] = s.y;             // M_{2k+1}
            }
        }
        __syncthreads();

        // ---- Phase C: series eval. f = tid&511, parity = tid>>9 (wave-uniform).
        // p_n = tau^n/n!; even threads n=0,2..62, odd threads n=1,3..63.
        {
            const int f   = tid & 511;
            const int par = tid >> 9;
            const float tau = s_c * xs[f] * s_scale;
            const float r2  = tau * tau;
            float den = 0.0f, num = 0.0f;
            if (par == 0) {
                float p = 1.0f;
                #pragma unroll
                for (int j = 0; j < 32; ++j) {
                    const int n = 2 * j;
                    den = fmaf(mom[n],     p, den);
                    num = fmaf(mom[n + 1], p, num);
                    p *= (1.0f / (float)((n + 1) * (n + 2)));  // literal
                    p *= r2;
                }
            } else {
                float p = tau;
                #pragma unroll
                for (int j = 0; j < 32; ++j) {
                    const int n = 2 * j + 1;
                    den = fmaf(mom[n],     p, den);
                    num = fmaf(mom[n + 1], p, num);
                    p *= (1.0f / (float)((n + 1) * (n + 2)));  // literal
                    p *= r2;
                }
            }
            v2f a; a.x = den; a.y = num;
            ((v2f*)pool)[tid] = a;                  // pow table is dead now
        }
        __syncthreads();
        if (tid < F_DIM) {
            const v2f a = ((v2f*)pool)[tid];
            const v2f b = ((v2f*)pool)[tid + 512];
            sf = s_scale * (a.y + b.y) / (a.x + b.x);
        }
    } else {
        // ---- Fallback: exact exp path (R6 kernel, verbatim) ----
        float (*pden)[F_DIM] = (float (*)[F_DIM])pool;
        float (*pnum)[F_DIM] = (float (*)[F_DIM])(pool + 4 * F_DIM);

        const float LOG2E = 1.4426950408889634f;
        const int f0 = (tid & 255) << 1;    // even f
        const int sl = tid >> 8;            // g-slice 0..3

        const float a0 = s_c * xs[f0]     * LOG2E;
        const float a1 = s_c * xs[f0 + 1] * LOG2E;
        v2f a2  = { a0, a1 };
        v2f bb  = { -((a0 >= 0.0f) ? a0 * s_xmax : a0 * s_xmin),
                    -((a1 >= 0.0f) ? a1 * s_xmax : a1 * s_xmin) };
        v2f den = { 0.0f, 0.0f };
        v2f num = { 0.0f, 0.0f };

        const float4* xs4 = (const float4*)&xs[sl << 7];
        #pragma unroll 8
        for (int i = 0; i < 32; ++i) {      // 32 broadcast ds_read_b128 = 128 g
            const float4 v = xs4[i];
            const float xg_[4] = { v.x, v.y, v.z, v.w };
            #pragma unroll
            for (int j = 0; j < 4; ++j) {
                const float xg = xg_[j];
                const v2f xg2 = { xg, xg };
                const v2f arg = __builtin_elementwise_fma(a2, xg2, bb);
                const v2f e   = { EXP2(arg.x), EXP2(arg.y) };
                den += e;
                num = __builtin_elementwise_fma(e, xg2, num);
            }
        }
        *(v2f*)&pden[sl][f0] = den;
        *(v2f*)&pnum[sl][f0] = num;
        __syncthreads();

        if (tid < F_DIM) {
            float D = 0.0f, N = 0.0f;
            #pragma unroll
            for (int s = 0; s < 4; ++s) { D += pden[s][tid]; N += pnum[s][tid]; }
            sf = N / D;
        }
    }

    // ---- Common epilogue: mean over f, scale by wv ----
    float t = sf;
    for (int o = 32; o > 0; o >>= 1) t += __shfl_down(t, o);
    if (lane == 0 && wave < 8) wsum[wave] = t;
    __syncthreads();

    if (tid < 128) {
        float total = 0.0f;
        #pragma unroll
        for (int i = 0; i < 8; ++i) total += wsum[i];
        out[row * 128 + tid] = total * (1.0f / (float)F_DIM) * wv[tid];
    }
}

extern "C" void kernel_launch(void* const* d_in, const int* in_sizes, int n_in,
                              void* d_out, int out_size, void* d_ws, size_t ws_size,
                              hipStream_t stream) {
    const float* x  = (const float*)d_in[0];  // [8,32,512]
    const float* wq = (const float*)d_in[1];  // [1,128]
    const float* wk = (const float*)d_in[2];  // [1,128]
    const float* wv = (const float*)d_in[3];  // [1,128]
    float* out = (float*)d_out;               // [8,32,128]

    intravol_attn<<<256, 1024, 0, stream>>>(x, wq, wk, wv, out);
}